// Round 3
// baseline (1154.254 us; speedup 1.0000x reference)
//
#include <hip/hip_runtime.h>
#include <stdint.h>
#include <stddef.h>

// GINE layer, MI355X -- round 3.
// R2 post-mortem: edge 167us @37% HBM; tail of 15 small dispatches ~530us.
// R3: CSR-walk edge kernel -- one wave owns 16 dst nodes, walks its sorted
// slot range, MFMA messages in 16-edge chunks, accumulates into per-wave
// private LDS tile (ds_add_f32, pad 132), writes h bf16 directly.
// Kills msg array (400MB round trip) + reduce_kernel. All intermediates
// bf16 (gemm A-frags load directly). swz merged to one dispatch.

#define NN 50000
#define EE 800000
#define DD 128
#define DE 64
#define H1 256
#define NGRP 3125   // NN/16 exactly

typedef __attribute__((ext_vector_type(8))) short short8;
typedef __attribute__((ext_vector_type(4))) float floatx4;

__device__ __forceinline__ short f2bf(float f) {
    union { float f; uint32_t u; } v; v.f = f;
    return (short)((v.u + 0x7FFFu + ((v.u >> 16) & 1u)) >> 16);  // RNE
}
__device__ __forceinline__ float bf2f(uint16_t u) {
    union { uint32_t u; float f; } v; v.u = (uint32_t)u << 16;
    return v.f;
}

// ---- merged weight swizzle: We(8192) + W1(32768) + W2(32768) items
__global__ __launch_bounds__(256) void swz_all_kernel(
    const float* __restrict__ We, const float* __restrict__ W1,
    const float* __restrict__ W2, short* __restrict__ dst) {
    int idx = blockIdx.x * 256 + threadIdx.x;
    if (idx >= 73728) return;
    const float* src; int KC, K, local; short* dp;
    if (idx < 8192)       { src = We; KC = 2; K = 64;  local = idx;          dp = dst; }
    else if (idx < 40960) { src = W1; KC = 4; K = 128; local = idx - 8192;  dp = dst + 8192; }
    else                  { src = W2; KC = 8; K = 256; local = idx - 40960; dp = dst + 40960; }
    int j = local & 7;
    int lane = (local >> 3) & 63;
    int f = local >> 9;
    int kc = f % KC;
    int nt = f / KC;
    int n = nt * 16 + (lane & 15);
    int k = kc * 32 + ((lane >> 4) & 3) * 8 + j;
    dp[local] = f2bf(src[(size_t)n * K + k]);
}

// ---- sort-by-dst machinery ----
__global__ __launch_bounds__(256) void count_kernel(const int* __restrict__ ei,
                                                    uint32_t* __restrict__ deg) {
    int e = blockIdx.x * 256 + threadIdx.x;
    atomicAdd(&deg[ei[EE + e]], 1u);
}

__global__ __launch_bounds__(256) void scan1_kernel(const uint32_t* __restrict__ deg,
                                                    uint32_t* __restrict__ partial) {
    __shared__ uint32_t ls[256];
    int i = blockIdx.x * 256 + threadIdx.x;
    ls[threadIdx.x] = deg[i];
    __syncthreads();
    for (int s = 128; s > 0; s >>= 1) {
        if (threadIdx.x < s) ls[threadIdx.x] += ls[threadIdx.x + s];
        __syncthreads();
    }
    if (threadIdx.x == 0) partial[blockIdx.x] = ls[0];
}

__global__ __launch_bounds__(256) void scan2_kernel(uint32_t* __restrict__ partial) {
    __shared__ uint32_t ls[196];
    if (threadIdx.x < 196) ls[threadIdx.x] = partial[threadIdx.x];
    __syncthreads();
    if (threadIdx.x == 0) {
        uint32_t run = 0;
        for (int i = 0; i < 196; ++i) { uint32_t t = ls[i]; ls[i] = run; run += t; }
    }
    __syncthreads();
    if (threadIdx.x < 196) partial[threadIdx.x] = ls[threadIdx.x];
}

__global__ __launch_bounds__(256) void scan3_kernel(const uint32_t* __restrict__ deg,
                                                    const uint32_t* __restrict__ partial,
                                                    uint32_t* __restrict__ base,
                                                    uint32_t* __restrict__ cursor) {
    __shared__ uint32_t ls[256];
    int i = blockIdx.x * 256 + threadIdx.x;
    uint32_t v = (i < NN) ? deg[i] : 0u;
    ls[threadIdx.x] = v;
    __syncthreads();
    for (int off = 1; off < 256; off <<= 1) {
        uint32_t t = (threadIdx.x >= off) ? ls[threadIdx.x - off] : 0u;
        __syncthreads();
        ls[threadIdx.x] += t;
        __syncthreads();
    }
    if (i < NN) {
        uint32_t b = partial[blockIdx.x] + ls[threadIdx.x] - v;  // exclusive
        base[i] = b;
        cursor[i] = b;
    } else if (i == NN) {
        base[NN] = EE;
    }
}

__global__ __launch_bounds__(256) void order_kernel(const int* __restrict__ ei,
                                                    uint32_t* __restrict__ cursor,
                                                    uint32_t* __restrict__ order) {
    int e = blockIdx.x * 256 + threadIdx.x;
    order[atomicAdd(&cursor[ei[EE + e]], 1u)] = (uint32_t)e;
}

// ---- fused edge + aggregate: one wave per 16-node dst group, CSR walk.
// msg chunk (16 edges) via MFMA; relu(x[src]+msg+be) accumulated into
// per-wave LDS tile [16][132] f32 via ds_add_f32; h written bf16.
__global__ __launch_bounds__(256) void edge_agg_kernel(
    const float* __restrict__ x,
    const int* __restrict__ ei,
    const float* __restrict__ ea,
    const short* __restrict__ weswz,
    const float* __restrict__ be,
    const uint32_t* __restrict__ order,
    const uint32_t* __restrict__ basep,   // [NN+1]
    const float* __restrict__ epsp,
    uint16_t* __restrict__ hbf)
{
    __shared__ float tile[4][16 * 132];
    const int wave = threadIdx.x >> 6;
    const int lane = threadIdx.x & 63;
    const int l16 = lane & 15;
    const int q = lane >> 4;
    const int grp = blockIdx.x * 4 + wave;
    if (grp >= NGRP) return;

    for (int i = lane; i < 16 * 132; i += 64) tile[wave][i] = 0.f;

    const short8* wp = (const short8*)weswz;
    short8 bfr[16];
#pragma unroll
    for (int f = 0; f < 16; ++f) bfr[f] = wp[f * 64 + lane];
    float bev[8];
#pragma unroll
    for (int t = 0; t < 8; ++t) bev[t] = be[t * 16 + l16];

    const int n0 = grp * 16;
    const int s0 = (int)basep[n0];
    const int s1 = (int)basep[n0 + 16];

    for (int s = s0; s < s1; s += 16) {
        // A-frag gather: lane l16 covers slot s+l16 (clamped for tail)
        int sa = s + l16;
        if (sa > s1 - 1) sa = s1 - 1;
        const uint32_t eA = order[sa];
        const float* earow = ea + (size_t)eA * DE + q * 8;
        floatx4 p0 = *(const floatx4*)(earow);
        floatx4 p1 = *(const floatx4*)(earow + 4);
        floatx4 p2 = *(const floatx4*)(earow + 32);
        floatx4 p3 = *(const floatx4*)(earow + 36);
        short8 af0, af1;
#pragma unroll
        for (int j = 0; j < 4; ++j) {
            af0[j]     = f2bf(p0[j]);
            af0[j + 4] = f2bf(p1[j]);
            af1[j]     = f2bf(p2[j]);
            af1[j + 4] = f2bf(p3[j]);
        }
        floatx4 acc[8];
#pragma unroll
        for (int t = 0; t < 8; ++t) {
            floatx4 z = {0.f, 0.f, 0.f, 0.f};
            z = __builtin_amdgcn_mfma_f32_16x16x32_bf16(af0, bfr[t * 2], z, 0, 0, 0);
            acc[t] = __builtin_amdgcn_mfma_f32_16x16x32_bf16(af1, bfr[t * 2 + 1], z, 0, 0, 0);
        }
        // epilogue: row (slot) = q*4+r, col = t*16+l16
#pragma unroll
        for (int r = 0; r < 4; ++r) {
            const int slot = s + q * 4 + r;
            if (slot < s1) {
                const uint32_t e = order[slot];
                const int src = ei[e];
                const int dl = ei[EE + e] - n0;
                const float* xr = x + (size_t)src * DD;
#pragma unroll
                for (int t = 0; t < 8; ++t) {
                    float v = acc[t][r] + bev[t] + xr[t * 16 + l16];
                    v = fmaxf(v, 0.f);
                    atomicAdd(&tile[wave][dl * 132 + t * 16 + l16], v);
                }
            }
        }
    }

    // finalize: h = (1+eps)*x + agg, write bf16. lane -> row=lane>>2, 32 cols
    const float c1 = 1.0f + epsp[0];
    const int row = lane >> 2;
    const int cq = (lane & 3) * 32;
    const float* xr = x + (size_t)(n0 + row) * DD + cq;
    uint16_t* hr = hbf + (size_t)(n0 + row) * DD + cq;
#pragma unroll
    for (int b = 0; b < 4; ++b) {
        floatx4 xa = *(const floatx4*)(xr + b * 8);
        floatx4 xb = *(const floatx4*)(xr + b * 8 + 4);
        const int off = row * 132 + cq + b * 8;
        uint32_t pk[4];
#pragma unroll
        for (int j = 0; j < 4; ++j) {
            float v0 = c1 * xa[j] + tile[wave][off + j];
            float v1 = c1 * xb[j] + tile[wave][off + 4 + j];
            if (j & 1) {
                pk[j >> 1]       |= ((uint32_t)(uint16_t)f2bf(v0)) << 16;
                pk[2 + (j >> 1)] |= ((uint32_t)(uint16_t)f2bf(v1)) << 16;
            } else {
                pk[j >> 1]       = (uint32_t)(uint16_t)f2bf(v0);
                pk[2 + (j >> 1)] = (uint32_t)(uint16_t)f2bf(v1);
            }
        }
        *(uint4*)(hr + b * 8) = make_uint4(pk[0], pk[1], pk[2], pk[3]);
    }
}

// ---- GEMM1: t1[N,256](bf16) = h @ W1^T + b1, fused BN1 stats
__global__ __launch_bounds__(256) void gemm1_kernel(
    const uint16_t* __restrict__ hbf,
    const short* __restrict__ w1swz,
    const float* __restrict__ b1,
    uint16_t* __restrict__ t1,
    float* __restrict__ gsum,
    float* __restrict__ gsq)
{
    __shared__ float ls[H1];
    __shared__ float ls2[H1];
    const int tid = threadIdx.x;
    ls[tid] = 0.f; ls2[tid] = 0.f;
    __syncthreads();

    const int wave = tid >> 6;
    const int lane = tid & 63;
    const int l16 = lane & 15;
    const int q = lane >> 4;
    const short8* wp = (const short8*)w1swz;

    const int grp = blockIdx.x * 4 + wave;
    if (grp < NGRP) {
        const int n0 = grp * 16;
        const uint16_t* hr = hbf + (size_t)(n0 + l16) * DD + q * 8;
        short8 af[4];
#pragma unroll
        for (int kc = 0; kc < 4; ++kc) af[kc] = *(const short8*)(hr + kc * 32);
#pragma unroll
        for (int nt = 0; nt < 16; ++nt) {
            floatx4 acc = {0.f, 0.f, 0.f, 0.f};
#pragma unroll
            for (int kc = 0; kc < 4; ++kc)
                acc = __builtin_amdgcn_mfma_f32_16x16x32_bf16(
                    af[kc], wp[(nt * 4 + kc) * 64 + lane], acc, 0, 0, 0);
            const float bb = b1[nt * 16 + l16];
            float s = 0.f, s2 = 0.f;
#pragma unroll
            for (int r = 0; r < 4; ++r) {
                float v = acc[r] + bb;
                t1[(size_t)(n0 + q * 4 + r) * H1 + nt * 16 + l16] = (uint16_t)f2bf(v);
                s += v; s2 += v * v;
            }
            atomicAdd(&ls[nt * 16 + l16], s);
            atomicAdd(&ls2[nt * 16 + l16], s2);
        }
    }
    __syncthreads();
    atomicAdd(&gsum[tid], ls[tid]);
    atomicAdd(&gsq[tid], ls2[tid]);
}

// ---- GEMM2: h2[N,128](bf16) = relu(t1*scale1+shift1) @ W2^T + b2, BN2 stats
__global__ __launch_bounds__(256) void gemm2_kernel(
    const uint16_t* __restrict__ t1,
    const float* __restrict__ scale1,
    const float* __restrict__ shift1,
    const short* __restrict__ w2swz,
    const float* __restrict__ b2,
    uint16_t* __restrict__ h2,
    float* __restrict__ gsum,
    float* __restrict__ gsq)
{
    __shared__ float ls[DD];
    __shared__ float ls2[DD];
    const int tid = threadIdx.x;
    if (tid < DD) { ls[tid] = 0.f; ls2[tid] = 0.f; }
    __syncthreads();

    const int wave = tid >> 6;
    const int lane = tid & 63;
    const int l16 = lane & 15;
    const int q = lane >> 4;
    const short8* wp = (const short8*)w2swz;

    const int grp = blockIdx.x * 4 + wave;
    if (grp < NGRP) {
        const int n0 = grp * 16;
        const uint16_t* tr = t1 + (size_t)(n0 + l16) * H1 + q * 8;
        floatx4 acc[8];
#pragma unroll
        for (int nt = 0; nt < 8; ++nt) acc[nt] = (floatx4){0.f, 0.f, 0.f, 0.f};
#pragma unroll
        for (int kc = 0; kc < 8; ++kc) {
            short8 tv = *(const short8*)(tr + kc * 32);
            const int kb = kc * 32 + q * 8;
            short8 af;
#pragma unroll
            for (int j = 0; j < 8; ++j) {
                float u = bf2f((uint16_t)tv[j]) * scale1[kb + j] + shift1[kb + j];
                af[j] = f2bf(fmaxf(u, 0.f));
            }
#pragma unroll
            for (int nt = 0; nt < 8; ++nt)
                acc[nt] = __builtin_amdgcn_mfma_f32_16x16x32_bf16(
                    af, wp[(nt * 8 + kc) * 64 + lane], acc[nt], 0, 0, 0);
        }
#pragma unroll
        for (int nt = 0; nt < 8; ++nt) {
            const float bb = b2[nt * 16 + l16];
            float s = 0.f, s2 = 0.f;
#pragma unroll
            for (int r = 0; r < 4; ++r) {
                float v = acc[nt][r] + bb;
                h2[(size_t)(n0 + q * 4 + r) * DD + nt * 16 + l16] = (uint16_t)f2bf(v);
                s += v; s2 += v * v;
            }
            atomicAdd(&ls[nt * 16 + l16], s);
            atomicAdd(&ls2[nt * 16 + l16], s2);
        }
    }
    __syncthreads();
    if (tid < DD) {
        atomicAdd(&gsum[tid], ls[tid]);
        atomicAdd(&gsq[tid], ls2[tid]);
    }
}

__global__ void finalize_kernel(const float* __restrict__ ssum,
                                const float* __restrict__ ssumsq,
                                const float* __restrict__ gamma,
                                const float* __restrict__ beta,
                                float* __restrict__ scale,
                                float* __restrict__ shift, int C) {
    int c = threadIdx.x;
    if (c >= C) return;
    float mu = ssum[c] * (1.0f / NN);
    float var = ssumsq[c] * (1.0f / NN) - mu * mu;
    float rs = rsqrtf(var + 1e-5f);
    float sc = gamma[c] * rs;
    scale[c] = sc;
    shift[c] = beta[c] - mu * sc;
}

__global__ __launch_bounds__(256) void out_kernel(const uint16_t* __restrict__ h2,
                                                  const float* __restrict__ scale2,
                                                  const float* __restrict__ shift2,
                                                  float* __restrict__ out) {
    int idx = blockIdx.x * 256 + threadIdx.x;
    int base = idx * 8;   // NN*DD = 6.4M, 800000 threads
    int c = base & (DD - 1);
    uint4 pk = *(const uint4*)(h2 + base);
    const uint32_t u[4] = {pk.x, pk.y, pk.z, pk.w};
    floatx4 o0, o1;
#pragma unroll
    for (int j = 0; j < 4; ++j) {
        float vlo = bf2f((uint16_t)(u[j] & 0xFFFFu));
        float vhi = bf2f((uint16_t)(u[j] >> 16));
        int cc = c + j * 2;
        float a = fmaxf(vlo * scale2[cc] + shift2[cc], 0.f);
        float b = fmaxf(vhi * scale2[cc + 1] + shift2[cc + 1], 0.f);
        if (j < 2) { o0[j * 2] = a; o0[j * 2 + 1] = b; }
        else       { o1[(j - 2) * 2] = a; o1[(j - 2) * 2 + 1] = b; }
    }
    *(floatx4*)(out + base) = o0;
    *(floatx4*)(out + base + 4) = o1;
}

extern "C" void kernel_launch(void* const* d_in, const int* in_sizes, int n_in,
                              void* d_out, int out_size, void* d_ws, size_t ws_size,
                              hipStream_t stream) {
    const float* x     = (const float*)d_in[0];
    const int*   ei    = (const int*)d_in[1];
    const float* ea    = (const float*)d_in[2];
    const float* We    = (const float*)d_in[3];
    const float* be    = (const float*)d_in[4];
    const float* W1    = (const float*)d_in[5];
    const float* b1    = (const float*)d_in[6];
    const float* g1    = (const float*)d_in[7];
    const float* beta1 = (const float*)d_in[8];
    const float* W2    = (const float*)d_in[9];
    const float* b2    = (const float*)d_in[10];
    const float* g2    = (const float*)d_in[11];
    const float* beta2 = (const float*)d_in[12];
    const float* epsp  = (const float*)d_in[13];

    float* ws      = (float*)d_ws;
    float* gsum1   = ws + 0;
    float* gsq1    = ws + 256;
    float* gsum2   = ws + 512;
    float* gsq2    = ws + 640;
    float* scale1  = ws + 768;
    float* shift1  = ws + 1024;
    float* scale2  = ws + 1280;
    float* shift2  = ws + 1408;
    uint32_t* deg     = (uint32_t*)(ws + 1536);   // 50176
    uint32_t* basep   = deg + 50176;              // 50432 (NN+1 used)
    uint32_t* cursor  = basep + 50432;            // 50176
    uint32_t* partial = cursor + 50176;           // 256
    uint32_t* order   = partial + 256;            // 800000
    uint16_t* hbf     = (uint16_t*)(order + EE);  // NN*DD
    uint16_t* t1      = hbf + (size_t)NN * DD;    // NN*H1
    uint16_t* h2      = t1 + (size_t)NN * H1;     // NN*DD
    short*    wswz    = (short*)(h2 + (size_t)NN * DD);  // 73728
    short*    weswz   = wswz;
    short*    w1swz   = wswz + 8192;
    short*    w2swz   = wswz + 40960;

    // zero stats (1536 f32) + deg (50176 u32), contiguous
    hipMemsetAsync(ws, 0, (1536 + 50176) * sizeof(uint32_t), stream);

    swz_all_kernel<<<dim3(288), 256, 0, stream>>>(We, W1, W2, wswz);
    count_kernel<<<dim3(3125), 256, 0, stream>>>(ei, deg);
    scan1_kernel<<<dim3(196), 256, 0, stream>>>(deg, partial);
    scan2_kernel<<<dim3(1), 256, 0, stream>>>(partial);
    scan3_kernel<<<dim3(196), 256, 0, stream>>>(deg, partial, basep, cursor);
    order_kernel<<<dim3(3125), 256, 0, stream>>>(ei, cursor, order);

    edge_agg_kernel<<<dim3(782), 256, 0, stream>>>(x, ei, ea, weswz, be, order,
                                                   basep, epsp, hbf);

    gemm1_kernel<<<dim3(782), 256, 0, stream>>>(hbf, w1swz, b1, t1, gsum1, gsq1);
    finalize_kernel<<<dim3(1), 256, 0, stream>>>(gsum1, gsq1, g1, beta1, scale1, shift1, H1);

    gemm2_kernel<<<dim3(782), 256, 0, stream>>>(t1, scale1, shift1, w2swz, b2, h2, gsum2, gsq2);
    finalize_kernel<<<dim3(1), 128, 0, stream>>>(gsum2, gsq2, g2, beta2, scale2, shift2, DD);

    out_kernel<<<dim3(3125), 256, 0, stream>>>(h2, scale2, shift2, (float*)d_out);
}

// Round 4
// 627.004 us; speedup vs baseline: 1.8409x; 1.8409x over previous
//
#include <hip/hip_runtime.h>
#include <stdint.h>
#include <stddef.h>

// GINE layer, MI355X -- round 4.
// R3 post-mortem: CSR-walk edge kernel was latency-hell (3128 waves, serial
// dependent chain per chunk; HBM 7%, VALU 3%). Reverted to R2's two-phase
// structure (10000 waves, independent chunks -> compiler pipelines loads).
// R4 deltas vs R2: bf16 intermediates everywhere (R3 win, kept), edge
// epilogue transposes through per-wave LDS tile and writes msg rows as
// contiguous 256B dwordx4 transactions (R2 scattered 2B stores), reduce
// unrolled x4 for memory-level parallelism. t1/h2 alias dead msg region.

#define NN 50000
#define EE 800000
#define DD 128
#define DE 64
#define H1 256
#define NGRP 3125   // NN/16 exactly

typedef __attribute__((ext_vector_type(8))) short short8;
typedef __attribute__((ext_vector_type(4))) float floatx4;

__device__ __forceinline__ short f2bf(float f) {
    union { float f; uint32_t u; } v; v.f = f;
    return (short)((v.u + 0x7FFFu + ((v.u >> 16) & 1u)) >> 16);  // RNE
}
__device__ __forceinline__ float bf2f(uint16_t u) {
    union { uint32_t u; float f; } v; v.u = (uint32_t)u << 16;
    return v.f;
}

// ---- merged weight swizzle: We(8192) + W1(32768) + W2(32768) items
__global__ __launch_bounds__(256) void swz_all_kernel(
    const float* __restrict__ We, const float* __restrict__ W1,
    const float* __restrict__ W2, short* __restrict__ dst) {
    int idx = blockIdx.x * 256 + threadIdx.x;
    if (idx >= 73728) return;
    const float* src; int KC, K, local; short* dp;
    if (idx < 8192)       { src = We; KC = 2; K = 64;  local = idx;          dp = dst; }
    else if (idx < 40960) { src = W1; KC = 4; K = 128; local = idx - 8192;  dp = dst + 8192; }
    else                  { src = W2; KC = 8; K = 256; local = idx - 40960; dp = dst + 40960; }
    int j = local & 7;
    int lane = (local >> 3) & 63;
    int f = local >> 9;
    int kc = f % KC;
    int nt = f / KC;
    int n = nt * 16 + (lane & 15);
    int k = kc * 32 + ((lane >> 4) & 3) * 8 + j;
    dp[local] = f2bf(src[(size_t)n * K + k]);
}

// ---- sort-by-dst machinery ----
__global__ __launch_bounds__(256) void count_kernel(const int* __restrict__ ei,
                                                    uint32_t* __restrict__ deg) {
    int e = blockIdx.x * 256 + threadIdx.x;
    atomicAdd(&deg[ei[EE + e]], 1u);
}

__global__ __launch_bounds__(256) void scan1_kernel(const uint32_t* __restrict__ deg,
                                                    uint32_t* __restrict__ partial) {
    __shared__ uint32_t ls[256];
    int i = blockIdx.x * 256 + threadIdx.x;
    ls[threadIdx.x] = deg[i];
    __syncthreads();
    for (int s = 128; s > 0; s >>= 1) {
        if (threadIdx.x < s) ls[threadIdx.x] += ls[threadIdx.x + s];
        __syncthreads();
    }
    if (threadIdx.x == 0) partial[blockIdx.x] = ls[0];
}

__global__ __launch_bounds__(256) void scan2_kernel(uint32_t* __restrict__ partial) {
    __shared__ uint32_t ls[196];
    if (threadIdx.x < 196) ls[threadIdx.x] = partial[threadIdx.x];
    __syncthreads();
    if (threadIdx.x == 0) {
        uint32_t run = 0;
        for (int i = 0; i < 196; ++i) { uint32_t t = ls[i]; ls[i] = run; run += t; }
    }
    __syncthreads();
    if (threadIdx.x < 196) partial[threadIdx.x] = ls[threadIdx.x];
}

__global__ __launch_bounds__(256) void scan3_kernel(const uint32_t* __restrict__ deg,
                                                    const uint32_t* __restrict__ partial,
                                                    uint32_t* __restrict__ base,
                                                    uint32_t* __restrict__ cursor) {
    __shared__ uint32_t ls[256];
    int i = blockIdx.x * 256 + threadIdx.x;
    uint32_t v = (i < NN) ? deg[i] : 0u;
    ls[threadIdx.x] = v;
    __syncthreads();
    for (int off = 1; off < 256; off <<= 1) {
        uint32_t t = (threadIdx.x >= off) ? ls[threadIdx.x - off] : 0u;
        __syncthreads();
        ls[threadIdx.x] += t;
        __syncthreads();
    }
    if (i < NN) {
        uint32_t b = partial[blockIdx.x] + ls[threadIdx.x] - v;  // exclusive
        base[i] = b;
        cursor[i] = b;
    } else if (i == NN) {
        base[NN] = EE;
    }
}

__global__ __launch_bounds__(256) void pos_kernel(const int* __restrict__ ei,
                                                  uint32_t* __restrict__ cursor,
                                                  uint32_t* __restrict__ pos) {
    int e = blockIdx.x * 256 + threadIdx.x;
    pos[e] = atomicAdd(&cursor[ei[EE + e]], 1u);
}

// ---- edge kernel: msg_row[pos[e]] = bf16(relu(x[src] + ea@We^T + be))
// Epilogue: transpose through per-wave LDS tile, write contiguous 256B rows.
#define EDGE_GPW 5
__global__ __launch_bounds__(256) void edge_kernel(
    const float* __restrict__ x,
    const int* __restrict__ ei,
    const float* __restrict__ ea,
    const short* __restrict__ weswz,
    const float* __restrict__ be,
    const uint32_t* __restrict__ pos,
    uint16_t* __restrict__ msg)
{
    __shared__ uint16_t tile[4][16 * 132];
    const int wave = threadIdx.x >> 6;
    const int lane = threadIdx.x & 63;
    const int l16 = lane & 15;
    const int q = lane >> 4;

    const short8* wp = (const short8*)weswz;
    short8 bfr[16];
#pragma unroll
    for (int f = 0; f < 16; ++f) bfr[f] = wp[f * 64 + lane];
    float bev[8];
#pragma unroll
    for (int t = 0; t < 8; ++t) bev[t] = be[t * 16 + l16];

    const int gbase = (blockIdx.x * 4 + wave) * EDGE_GPW;
    for (int g = 0; g < EDGE_GPW; ++g) {
        const int e0 = (gbase + g) * 16;
        const float* earow = ea + (size_t)(e0 + l16) * DE + q * 8;
        floatx4 p0 = *(const floatx4*)(earow);
        floatx4 p1 = *(const floatx4*)(earow + 4);
        floatx4 p2 = *(const floatx4*)(earow + 32);
        floatx4 p3 = *(const floatx4*)(earow + 36);
        short8 af0, af1;
#pragma unroll
        for (int j = 0; j < 4; ++j) {
            af0[j]     = f2bf(p0[j]);
            af0[j + 4] = f2bf(p1[j]);
            af1[j]     = f2bf(p2[j]);
            af1[j + 4] = f2bf(p3[j]);
        }
        floatx4 acc[8];
#pragma unroll
        for (int t = 0; t < 8; ++t) {
            floatx4 z = {0.f, 0.f, 0.f, 0.f};
            z = __builtin_amdgcn_mfma_f32_16x16x32_bf16(af0, bfr[t * 2], z, 0, 0, 0);
            acc[t] = __builtin_amdgcn_mfma_f32_16x16x32_bf16(af1, bfr[t * 2 + 1], z, 0, 0, 0);
        }
        // phase 1: gather x, add bias, relu, pack bf16 into LDS tile
        // tile row = chunk-local edge (q*4+r), col = t*16+l16
#pragma unroll
        for (int r = 0; r < 4; ++r) {
            const int e = e0 + q * 4 + r;
            const int s = ei[e];
            const float* xr = x + (size_t)s * DD;
#pragma unroll
            for (int t = 0; t < 8; ++t) {
                float v = fmaxf(acc[t][r] + bev[t] + xr[t * 16 + l16], 0.f);
                tile[wave][(q * 4 + r) * 132 + t * 16 + l16] = (uint16_t)f2bf(v);
            }
        }
        __asm__ volatile("s_waitcnt lgkmcnt(0)" ::: "memory");
        // phase 2: write 16 rows, each as 16 lanes x dwordx4 (256B contiguous)
#pragma unroll
        for (int p = 0; p < 4; ++p) {
            const int row = p * 4 + q;
            const uint32_t pp = pos[e0 + row];
            uint4 val = *(const uint4*)&tile[wave][row * 132 + l16 * 8];
            *(uint4*)(msg + (size_t)pp * DD + l16 * 8) = val;
        }
        __asm__ volatile("s_waitcnt vmcnt(0)" ::: "memory");  // tile reuse safety
    }
}

// ---- segment reduce: h[n] = (1+eps)*x[n] + sum(msg rows), x4 unrolled
__global__ __launch_bounds__(256) void reduce_kernel(
    const uint16_t* __restrict__ msg,
    const uint32_t* __restrict__ basep,
    const float* __restrict__ x,
    const float* __restrict__ epsp,
    uint16_t* __restrict__ hbf)
{
    const int n = blockIdx.x * 4 + (threadIdx.x >> 6);
    const int lane = threadIdx.x & 63;
    const uint32_t b0 = basep[n];
    const uint32_t d = basep[n + 1] - b0;
    const uint32_t* mp = (const uint32_t*)msg + (size_t)b0 * 64 + lane;
    float s0a = 0.f, s1a = 0.f, s0b = 0.f, s1b = 0.f;
    float s0c = 0.f, s1c = 0.f, s0d = 0.f, s1d = 0.f;
    uint32_t i = 0;
    for (; i + 4 <= d; i += 4) {
        uint32_t u0 = mp[(size_t)(i + 0) * 64];
        uint32_t u1 = mp[(size_t)(i + 1) * 64];
        uint32_t u2 = mp[(size_t)(i + 2) * 64];
        uint32_t u3 = mp[(size_t)(i + 3) * 64];
        s0a += bf2f((uint16_t)(u0 & 0xFFFFu)); s1a += bf2f((uint16_t)(u0 >> 16));
        s0b += bf2f((uint16_t)(u1 & 0xFFFFu)); s1b += bf2f((uint16_t)(u1 >> 16));
        s0c += bf2f((uint16_t)(u2 & 0xFFFFu)); s1c += bf2f((uint16_t)(u2 >> 16));
        s0d += bf2f((uint16_t)(u3 & 0xFFFFu)); s1d += bf2f((uint16_t)(u3 >> 16));
    }
    for (; i < d; ++i) {
        uint32_t u = mp[(size_t)i * 64];
        s0a += bf2f((uint16_t)(u & 0xFFFFu)); s1a += bf2f((uint16_t)(u >> 16));
    }
    float s0 = (s0a + s0b) + (s0c + s0d);
    float s1 = (s1a + s1b) + (s1c + s1d);
    const float c1 = 1.0f + epsp[0];
    const int idx = n * DD + lane * 2;
    float2 xv = *(const float2*)(x + idx);
    uint32_t pk = (uint32_t)(uint16_t)f2bf(c1 * xv.x + s0) |
                  ((uint32_t)(uint16_t)f2bf(c1 * xv.y + s1) << 16);
    ((uint32_t*)hbf)[idx >> 1] = pk;
}

// ---- GEMM1: t1[N,256](bf16) = h @ W1^T + b1, fused BN1 stats
__global__ __launch_bounds__(256) void gemm1_kernel(
    const uint16_t* __restrict__ hbf,
    const short* __restrict__ w1swz,
    const float* __restrict__ b1,
    uint16_t* __restrict__ t1,
    float* __restrict__ gsum,
    float* __restrict__ gsq)
{
    __shared__ float ls[H1];
    __shared__ float ls2[H1];
    const int tid = threadIdx.x;
    ls[tid] = 0.f; ls2[tid] = 0.f;
    __syncthreads();

    const int wave = tid >> 6;
    const int lane = tid & 63;
    const int l16 = lane & 15;
    const int q = lane >> 4;
    const short8* wp = (const short8*)w1swz;

    const int grp = blockIdx.x * 4 + wave;
    if (grp < NGRP) {
        const int n0 = grp * 16;
        const uint16_t* hr = hbf + (size_t)(n0 + l16) * DD + q * 8;
        short8 af[4];
#pragma unroll
        for (int kc = 0; kc < 4; ++kc) af[kc] = *(const short8*)(hr + kc * 32);
#pragma unroll
        for (int nt = 0; nt < 16; ++nt) {
            floatx4 acc = {0.f, 0.f, 0.f, 0.f};
#pragma unroll
            for (int kc = 0; kc < 4; ++kc)
                acc = __builtin_amdgcn_mfma_f32_16x16x32_bf16(
                    af[kc], wp[(nt * 4 + kc) * 64 + lane], acc, 0, 0, 0);
            const float bb = b1[nt * 16 + l16];
            float s = 0.f, s2 = 0.f;
#pragma unroll
            for (int r = 0; r < 4; ++r) {
                float v = acc[r] + bb;
                t1[(size_t)(n0 + q * 4 + r) * H1 + nt * 16 + l16] = (uint16_t)f2bf(v);
                s += v; s2 += v * v;
            }
            atomicAdd(&ls[nt * 16 + l16], s);
            atomicAdd(&ls2[nt * 16 + l16], s2);
        }
    }
    __syncthreads();
    atomicAdd(&gsum[tid], ls[tid]);
    atomicAdd(&gsq[tid], ls2[tid]);
}

// ---- GEMM2: h2[N,128](bf16) = relu(t1*scale1+shift1) @ W2^T + b2, BN2 stats
__global__ __launch_bounds__(256) void gemm2_kernel(
    const uint16_t* __restrict__ t1,
    const float* __restrict__ scale1,
    const float* __restrict__ shift1,
    const short* __restrict__ w2swz,
    const float* __restrict__ b2,
    uint16_t* __restrict__ h2,
    float* __restrict__ gsum,
    float* __restrict__ gsq)
{
    __shared__ float ls[DD];
    __shared__ float ls2[DD];
    const int tid = threadIdx.x;
    if (tid < DD) { ls[tid] = 0.f; ls2[tid] = 0.f; }
    __syncthreads();

    const int wave = tid >> 6;
    const int lane = tid & 63;
    const int l16 = lane & 15;
    const int q = lane >> 4;
    const short8* wp = (const short8*)w2swz;

    const int grp = blockIdx.x * 4 + wave;
    if (grp < NGRP) {
        const int n0 = grp * 16;
        const uint16_t* tr = t1 + (size_t)(n0 + l16) * H1 + q * 8;
        floatx4 acc[8];
#pragma unroll
        for (int nt = 0; nt < 8; ++nt) acc[nt] = (floatx4){0.f, 0.f, 0.f, 0.f};
#pragma unroll
        for (int kc = 0; kc < 8; ++kc) {
            short8 tv = *(const short8*)(tr + kc * 32);
            const int kb = kc * 32 + q * 8;
            short8 af;
#pragma unroll
            for (int j = 0; j < 8; ++j) {
                float u = bf2f((uint16_t)tv[j]) * scale1[kb + j] + shift1[kb + j];
                af[j] = f2bf(fmaxf(u, 0.f));
            }
#pragma unroll
            for (int nt = 0; nt < 8; ++nt)
                acc[nt] = __builtin_amdgcn_mfma_f32_16x16x32_bf16(
                    af, wp[(nt * 8 + kc) * 64 + lane], acc[nt], 0, 0, 0);
        }
#pragma unroll
        for (int nt = 0; nt < 8; ++nt) {
            const float bb = b2[nt * 16 + l16];
            float s = 0.f, s2 = 0.f;
#pragma unroll
            for (int r = 0; r < 4; ++r) {
                float v = acc[nt][r] + bb;
                h2[(size_t)(n0 + q * 4 + r) * DD + nt * 16 + l16] = (uint16_t)f2bf(v);
                s += v; s2 += v * v;
            }
            atomicAdd(&ls[nt * 16 + l16], s);
            atomicAdd(&ls2[nt * 16 + l16], s2);
        }
    }
    __syncthreads();
    if (tid < DD) {
        atomicAdd(&gsum[tid], ls[tid]);
        atomicAdd(&gsq[tid], ls2[tid]);
    }
}

__global__ void finalize_kernel(const float* __restrict__ ssum,
                                const float* __restrict__ ssumsq,
                                const float* __restrict__ gamma,
                                const float* __restrict__ beta,
                                float* __restrict__ scale,
                                float* __restrict__ shift, int C) {
    int c = threadIdx.x;
    if (c >= C) return;
    float mu = ssum[c] * (1.0f / NN);
    float var = ssumsq[c] * (1.0f / NN) - mu * mu;
    float rs = rsqrtf(var + 1e-5f);
    float sc = gamma[c] * rs;
    scale[c] = sc;
    shift[c] = beta[c] - mu * sc;
}

__global__ __launch_bounds__(256) void out_kernel(const uint16_t* __restrict__ h2,
                                                  const float* __restrict__ scale2,
                                                  const float* __restrict__ shift2,
                                                  float* __restrict__ out) {
    int idx = blockIdx.x * 256 + threadIdx.x;
    int base = idx * 8;   // NN*DD = 6.4M elems, 800000 threads
    int c = base & (DD - 1);
    uint4 pk = *(const uint4*)(h2 + base);
    const uint32_t u[4] = {pk.x, pk.y, pk.z, pk.w};
    floatx4 o0, o1;
#pragma unroll
    for (int j = 0; j < 4; ++j) {
        float vlo = bf2f((uint16_t)(u[j] & 0xFFFFu));
        float vhi = bf2f((uint16_t)(u[j] >> 16));
        int cc = c + j * 2;
        float a = fmaxf(vlo * scale2[cc] + shift2[cc], 0.f);
        float b = fmaxf(vhi * scale2[cc + 1] + shift2[cc + 1], 0.f);
        if (j < 2) { o0[j * 2] = a; o0[j * 2 + 1] = b; }
        else       { o1[(j - 2) * 2] = a; o1[(j - 2) * 2 + 1] = b; }
    }
    *(floatx4*)(out + base) = o0;
    *(floatx4*)(out + base + 4) = o1;
}

extern "C" void kernel_launch(void* const* d_in, const int* in_sizes, int n_in,
                              void* d_out, int out_size, void* d_ws, size_t ws_size,
                              hipStream_t stream) {
    const float* x     = (const float*)d_in[0];
    const int*   ei    = (const int*)d_in[1];
    const float* ea    = (const float*)d_in[2];
    const float* We    = (const float*)d_in[3];
    const float* be    = (const float*)d_in[4];
    const float* W1    = (const float*)d_in[5];
    const float* b1    = (const float*)d_in[6];
    const float* g1    = (const float*)d_in[7];
    const float* beta1 = (const float*)d_in[8];
    const float* W2    = (const float*)d_in[9];
    const float* b2    = (const float*)d_in[10];
    const float* g2    = (const float*)d_in[11];
    const float* beta2 = (const float*)d_in[12];
    const float* epsp  = (const float*)d_in[13];

    float* ws      = (float*)d_ws;
    float* gsum1   = ws + 0;
    float* gsq1    = ws + 256;
    float* gsum2   = ws + 512;
    float* gsq2    = ws + 640;
    float* scale1  = ws + 768;
    float* shift1  = ws + 1024;
    float* scale2  = ws + 1280;
    float* shift2  = ws + 1408;
    uint32_t* deg     = (uint32_t*)(ws + 1536);   // 50176
    uint32_t* basep   = deg + 50176;              // 50432 (NN+1 used)
    uint32_t* cursor  = basep + 50432;            // 50176
    uint32_t* partial = cursor + 50176;           // 256
    uint32_t* pos     = partial + 256;            // 800000
    uint16_t* hbf     = (uint16_t*)(pos + EE);    // NN*DD
    uint16_t* msg     = hbf + (size_t)NN * DD;    // EE*DD bf16 (204.8 MB)
    uint16_t* t1      = msg;                      // alias: msg dead after reduce
    uint16_t* h2      = t1 + (size_t)NN * H1;
    short*    wswz    = (short*)(msg + (size_t)EE * DD);  // 73728
    short*    weswz   = wswz;
    short*    w1swz   = wswz + 8192;
    short*    w2swz   = wswz + 40960;

    // zero stats (1536 f32) + deg (50176 u32), contiguous
    hipMemsetAsync(ws, 0, (1536 + 50176) * sizeof(uint32_t), stream);

    swz_all_kernel<<<dim3(288), 256, 0, stream>>>(We, W1, W2, wswz);
    count_kernel<<<dim3(3125), 256, 0, stream>>>(ei, deg);
    scan1_kernel<<<dim3(196), 256, 0, stream>>>(deg, partial);
    scan2_kernel<<<dim3(1), 256, 0, stream>>>(partial);
    scan3_kernel<<<dim3(196), 256, 0, stream>>>(deg, partial, basep, cursor);
    pos_kernel<<<dim3(3125), 256, 0, stream>>>(ei, cursor, pos);

    edge_kernel<<<dim3(2500), 256, 0, stream>>>(x, ei, ea, weswz, be, pos, msg);
    reduce_kernel<<<dim3(12500), 256, 0, stream>>>(msg, basep, x, epsp, hbf);

    gemm1_kernel<<<dim3(782), 256, 0, stream>>>(hbf, w1swz, b1, t1, gsum1, gsq1);
    finalize_kernel<<<dim3(1), 256, 0, stream>>>(gsum1, gsq1, g1, beta1, scale1, shift1, H1);

    gemm2_kernel<<<dim3(782), 256, 0, stream>>>(t1, scale1, shift1, w2swz, b2, h2, gsum2, gsq2);
    finalize_kernel<<<dim3(1), 128, 0, stream>>>(gsum2, gsq2, g2, beta2, scale2, shift2, DD);

    out_kernel<<<dim3(3125), 256, 0, stream>>>(h2, scale2, shift2, (float*)d_out);
}